// Round 2
// baseline (49.664 us; speedup 1.0000x reference)
//
#include <hip/hip_runtime.h>

#define N_SQ   32
#define N_PTS  2000000
#define PSTRIDE 21   // padded LDS row stride (gcd(21,32)=1 -> conflict-free gathers)

__global__ __launch_bounds__(256) void superq_sdf_kernel(
    const float* __restrict__ points,
    const float* __restrict__ raw_sqscale,
    const float* __restrict__ raw_exponents,
    const float* __restrict__ raw_rotation,
    const float* __restrict__ translation,
    const int*   __restrict__ assign,
    float*       __restrict__ out)
{
    __shared__ float P[N_SQ * PSTRIDE];

    // --- per-block SQ parameter precompute (32 lanes, trivial cost) ---
    int tid = threadIdx.x;
    if (tid < N_SQ) {
        int q = tid;
        // raw_rotation layout: [q][i][j], j in {0,1} -> a1_i = [q*6+i*2], a2_i = [q*6+i*2+1]
        float a1x = raw_rotation[q*6 + 0], a2x = raw_rotation[q*6 + 1];
        float a1y = raw_rotation[q*6 + 2], a2y = raw_rotation[q*6 + 3];
        float a1z = raw_rotation[q*6 + 4], a2z = raw_rotation[q*6 + 5];
        float n1   = sqrtf(a1x*a1x + a1y*a1y + a1z*a1z);
        float inv1 = 1.0f / fmaxf(n1, 1e-12f);
        float b1x = a1x*inv1, b1y = a1y*inv1, b1z = a1z*inv1;
        float d   = b1x*a2x + b1y*a2y + b1z*a2z;
        float b2x = a2x - d*b1x, b2y = a2y - d*b1y, b2z = a2z - d*b1z;
        float n2   = sqrtf(b2x*b2x + b2y*b2y + b2z*b2z);
        float inv2 = 1.0f / fmaxf(n2, 1e-12f);
        b2x *= inv2; b2y *= inv2; b2z *= inv2;
        float b3x = b1y*b2z - b1z*b2y;
        float b3y = b1z*b2x - b1x*b2z;
        float b3z = b1x*b2y - b1y*b2x;
        float s0 = fmaxf(raw_sqscale[q*3 + 0], 1e-5f);
        float s1 = fmaxf(raw_sqscale[q*3 + 1], 1e-5f);
        float s2 = fmaxf(raw_sqscale[q*3 + 2], 1e-5f);
        float e1 = fmaxf(raw_exponents[q*2 + 0], 0.01f);
        float e2 = fmaxf(raw_exponents[q*2 + 1], 0.01f);
        float* row = &P[q * PSTRIDE];
        row[0]  = b1x; row[1]  = b1y; row[2]  = b1z;
        row[3]  = b2x; row[4]  = b2y; row[5]  = b2z;
        row[6]  = b3x; row[7]  = b3y; row[8]  = b3z;
        row[9]  = translation[q*3 + 0];
        row[10] = translation[q*3 + 1];
        row[11] = translation[q*3 + 2];
        row[12] = 1.0f / s0;
        row[13] = 1.0f / s1;
        row[14] = 1.0f / s2;
        row[15] = 1.0f / e1;     // inv_e1
        row[16] = 1.0f / e2;     // inv_e2
        row[17] = e2 / e1;       // e2/e1
        row[18] = -0.5f * e1;    // -e1/2
    }
    __syncthreads();

    long long t  = (long long)blockIdx.x * blockDim.x + threadIdx.x;
    long long p4 = t * 4;
    if (p4 >= N_PTS) return;

    // --- segment lookup: 32 coalesced int4 rows of the one-hot matrix ---
    int seg0 = -1, seg1 = -1, seg2 = -1, seg3 = -1;
    const int4* amv = (const int4*)assign;
    long long col = p4 >> 2;
    #pragma unroll
    for (int q = 0; q < N_SQ; ++q) {
        int4 a = amv[(long long)q * (N_PTS / 4) + col];
        if (seg0 < 0 && a.x == 1) seg0 = q;
        if (seg1 < 0 && a.y == 1) seg1 = q;
        if (seg2 < 0 && a.z == 1) seg2 = q;
        if (seg3 < 0 && a.w == 1) seg3 = q;
    }
    int seg[4] = {seg0, seg1, seg2, seg3};

    // --- load 4 points (12 floats) as 3x float4 ---
    const float4* pv = (const float4*)(points + p4 * 3);
    float4 v0 = pv[0], v1 = pv[1], v2 = pv[2];
    float px[4] = {v0.x, v0.w, v1.z, v2.y};
    float py[4] = {v0.y, v1.x, v1.w, v2.z};
    float pz[4] = {v0.z, v1.y, v2.x, v2.w};

    float res[4];
    #pragma unroll
    for (int k = 0; k < 4; ++k) {
        int sq = seg[k];
        if (sq < 0) { res[k] = 0.0f; continue; }
        const float* row = &P[sq * PSTRIDE];
        float cx = px[k] - row[9];
        float cy = py[k] - row[10];
        float cz = pz[k] - row[11];
        float X0 = row[0]*cx + row[1]*cy + row[2]*cz;
        float X1 = row[3]*cx + row[4]*cy + row[5]*cz;
        float X2 = row[6]*cx + row[7]*cy + row[8]*cz;
        float A0 = fmaxf(fabsf(X0), 1e-6f);
        float A1 = fmaxf(fabsf(X1), 1e-6f);
        float A2 = fmaxf(fabsf(X2), 1e-6f);
        float r0 = sqrtf(A0*A0 + A1*A1 + A2*A2);
        float u0 = A0 * row[12];
        float u1 = A1 * row[13];
        float u2 = A2 * row[14];
        // term = (u^2)^(1/e)  via hardware log2/exp2 (~1 ulp; tolerance 2e-3)
        float t1 = __builtin_amdgcn_exp2f(row[16] * __builtin_amdgcn_logf(u0*u0));
        float t2 = __builtin_amdgcn_exp2f(row[16] * __builtin_amdgcn_logf(u1*u1));
        float t3 = __builtin_amdgcn_exp2f(row[15] * __builtin_amdgcn_logf(u2*u2));
        float inner = __builtin_amdgcn_exp2f(row[17] * __builtin_amdgcn_logf(t1 + t2)) + t3;
        float f  = __builtin_amdgcn_exp2f(row[18] * __builtin_amdgcn_logf(inner));
        float sdf = r0 * (1.0f - f);
        sdf = fminf(fmaxf(sdf, -0.1f), 0.1f);
        res[k] = sdf;
    }

    *(float4*)(out + p4) = make_float4(res[0], res[1], res[2], res[3]);
}

extern "C" void kernel_launch(void* const* d_in, const int* in_sizes, int n_in,
                              void* d_out, int out_size, void* d_ws, size_t ws_size,
                              hipStream_t stream) {
    const float* points        = (const float*)d_in[0];
    const float* raw_sqscale   = (const float*)d_in[1];
    const float* raw_exponents = (const float*)d_in[2];
    const float* raw_rotation  = (const float*)d_in[3];
    const float* translation   = (const float*)d_in[4];
    const int*   assign        = (const int*)d_in[5];
    float*       out           = (float*)d_out;

    int threads = N_PTS / 4;                 // 500,000 threads, 4 points each
    int blocks  = (threads + 255) / 256;     // 1954
    superq_sdf_kernel<<<blocks, 256, 0, stream>>>(
        points, raw_sqscale, raw_exponents, raw_rotation, translation, assign, out);
}

// Round 4
// 48.105 us; speedup vs baseline: 1.0324x; 1.0324x over previous
//
#include <hip/hip_runtime.h>

#define N_SQ    32
#define N_PTS   2000000
#define NCOL4   (N_PTS / 4)   // 500000 int4 columns per assign row
#define PSTRIDE 21            // padded LDS row stride (gcd(21,32)=1 -> low-conflict gathers)

typedef float __attribute__((ext_vector_type(4))) f32x4;
typedef int   __attribute__((ext_vector_type(4))) i32x4;

// Accumulate CNT one-hot rows starting at Q0 into seg-sum s[] and found-count f[].
// One-hot values are exactly 0/1, so seg = sum(q * a_q), found = sum(a_q).
template<int Q0, int CNT>
__device__ __forceinline__ void accum_chunk(const i32x4* __restrict__ amv, int col,
                                            int* __restrict__ s, int* __restrict__ f)
{
    i32x4 a[CNT];
    #pragma unroll
    for (int j = 0; j < CNT; ++j)
        a[j] = __builtin_nontemporal_load(amv + (Q0 + j) * NCOL4 + col);
    #pragma unroll
    for (int j = 0; j < CNT; ++j) {
        const int q = Q0 + j;
        #pragma unroll
        for (int k = 0; k < 4; ++k) {
            s[k] += q * a[j][k];
            f[k] += a[j][k];
        }
    }
}

__global__ __launch_bounds__(256) void superq_sdf_kernel(
    const float* __restrict__ points,
    const float* __restrict__ raw_sqscale,
    const float* __restrict__ raw_exponents,
    const float* __restrict__ raw_rotation,
    const float* __restrict__ translation,
    const int*   __restrict__ assign,
    float*       __restrict__ out)
{
    __shared__ float P[N_SQ * PSTRIDE];

    // --- per-block SQ parameter precompute (32 lanes, trivial cost) ---
    int tid = threadIdx.x;
    if (tid < N_SQ) {
        int q = tid;
        // raw_rotation layout: [q][i][j], j in {0,1}
        float a1x = raw_rotation[q*6 + 0], a2x = raw_rotation[q*6 + 1];
        float a1y = raw_rotation[q*6 + 2], a2y = raw_rotation[q*6 + 3];
        float a1z = raw_rotation[q*6 + 4], a2z = raw_rotation[q*6 + 5];
        float n1   = sqrtf(a1x*a1x + a1y*a1y + a1z*a1z);
        float inv1 = 1.0f / fmaxf(n1, 1e-12f);
        float b1x = a1x*inv1, b1y = a1y*inv1, b1z = a1z*inv1;
        float d   = b1x*a2x + b1y*a2y + b1z*a2z;
        float b2x = a2x - d*b1x, b2y = a2y - d*b1y, b2z = a2z - d*b1z;
        float n2   = sqrtf(b2x*b2x + b2y*b2y + b2z*b2z);
        float inv2 = 1.0f / fmaxf(n2, 1e-12f);
        b2x *= inv2; b2y *= inv2; b2z *= inv2;
        float b3x = b1y*b2z - b1z*b2y;
        float b3y = b1z*b2x - b1x*b2z;
        float b3z = b1x*b2y - b1y*b2x;
        float s0 = fmaxf(raw_sqscale[q*3 + 0], 1e-5f);
        float s1 = fmaxf(raw_sqscale[q*3 + 1], 1e-5f);
        float s2 = fmaxf(raw_sqscale[q*3 + 2], 1e-5f);
        float e1 = fmaxf(raw_exponents[q*2 + 0], 0.01f);
        float e2 = fmaxf(raw_exponents[q*2 + 1], 0.01f);
        float* row = &P[q * PSTRIDE];
        row[0]  = b1x; row[1]  = b1y; row[2]  = b1z;
        row[3]  = b2x; row[4]  = b2y; row[5]  = b2z;
        row[6]  = b3x; row[7]  = b3y; row[8]  = b3z;
        row[9]  = translation[q*3 + 0];
        row[10] = translation[q*3 + 1];
        row[11] = translation[q*3 + 2];
        row[12] = 1.0f / s0;
        row[13] = 1.0f / s1;
        row[14] = 1.0f / s2;
        row[15] = 1.0f / e1;     // inv_e1
        row[16] = 1.0f / e2;     // inv_e2
        row[17] = e2 / e1;       // e2/e1
        row[18] = -0.5f * e1;    // -e1/2
    }
    __syncthreads();

    int col = blockIdx.x * blockDim.x + threadIdx.x;   // one int4 column (4 points)
    if (col >= NCOL4) return;
    int p4 = col * 4;

    // --- load 4 points (12 floats) as 3x float4, issued before the assign stream ---
    const f32x4* pv = (const f32x4*)(points + (long long)p4 * 3);
    f32x4 v0 = __builtin_nontemporal_load(pv + 0);
    f32x4 v1 = __builtin_nontemporal_load(pv + 1);
    f32x4 v2 = __builtin_nontemporal_load(pv + 2);

    // --- segment lookup: rows 0..30 coalesced; row 31 inferred (matrix is one-hot) ---
    const i32x4* amv = (const i32x4*)assign;
    int s[4] = {0,0,0,0}, f[4] = {0,0,0,0};
    accum_chunk<0, 8>(amv, col, s, f);
    accum_chunk<8, 8>(amv, col, s, f);
    accum_chunk<16,8>(amv, col, s, f);
    accum_chunk<24,7>(amv, col, s, f);

    int seg[4];
    #pragma unroll
    for (int k = 0; k < 4; ++k) seg[k] = f[k] ? s[k] : 31;

    float px[4] = {v0.x, v0.w, v1.z, v2.y};
    float py[4] = {v0.y, v1.x, v1.w, v2.z};
    float pz[4] = {v0.z, v1.y, v2.x, v2.w};

    float res[4];
    #pragma unroll
    for (int k = 0; k < 4; ++k) {
        const float* row = &P[seg[k] * PSTRIDE];
        float cx = px[k] - row[9];
        float cy = py[k] - row[10];
        float cz = pz[k] - row[11];
        float X0 = row[0]*cx + row[1]*cy + row[2]*cz;
        float X1 = row[3]*cx + row[4]*cy + row[5]*cz;
        float X2 = row[6]*cx + row[7]*cy + row[8]*cz;
        float A0 = fmaxf(fabsf(X0), 1e-6f);
        float A1 = fmaxf(fabsf(X1), 1e-6f);
        float A2 = fmaxf(fabsf(X2), 1e-6f);
        float r0 = sqrtf(A0*A0 + A1*A1 + A2*A2);
        float u0 = A0 * row[12];
        float u1 = A1 * row[13];
        float u2 = A2 * row[14];
        // term = (u^2)^(1/e) via hardware log2/exp2 (~1 ulp; tolerance 2e-3)
        float t1 = __builtin_amdgcn_exp2f(row[16] * __builtin_amdgcn_logf(u0*u0));
        float t2 = __builtin_amdgcn_exp2f(row[16] * __builtin_amdgcn_logf(u1*u1));
        float t3 = __builtin_amdgcn_exp2f(row[15] * __builtin_amdgcn_logf(u2*u2));
        float inner = __builtin_amdgcn_exp2f(row[17] * __builtin_amdgcn_logf(t1 + t2)) + t3;
        float fq  = __builtin_amdgcn_exp2f(row[18] * __builtin_amdgcn_logf(inner));
        float sdf = r0 * (1.0f - fq);
        sdf = fminf(fmaxf(sdf, -0.1f), 0.1f);
        res[k] = sdf;
    }

    f32x4 r;
    r.x = res[0]; r.y = res[1]; r.z = res[2]; r.w = res[3];
    __builtin_nontemporal_store(r, (f32x4*)(out + p4));
}

extern "C" void kernel_launch(void* const* d_in, const int* in_sizes, int n_in,
                              void* d_out, int out_size, void* d_ws, size_t ws_size,
                              hipStream_t stream) {
    const float* points        = (const float*)d_in[0];
    const float* raw_sqscale   = (const float*)d_in[1];
    const float* raw_exponents = (const float*)d_in[2];
    const float* raw_rotation  = (const float*)d_in[3];
    const float* translation   = (const float*)d_in[4];
    const int*   assign        = (const int*)d_in[5];
    float*       out           = (float*)d_out;

    int blocks = (NCOL4 + 255) / 256;   // 1954 blocks of 256 threads, 4 points/thread
    superq_sdf_kernel<<<blocks, 256, 0, stream>>>(
        points, raw_sqscale, raw_exponents, raw_rotation, translation, assign, out);
}